// Round 5
// baseline (775.566 us; speedup 1.0000x reference)
//
#include <hip/hip_runtime.h>
#include <hip/hip_bf16.h>
#include <stdint.h>

typedef __bf16 bf16x8 __attribute__((ext_vector_type(8)));
typedef __bf16 bf16x4 __attribute__((ext_vector_type(4)));
typedef float  f32x4  __attribute__((ext_vector_type(4)));

#define B_  16
#define KL  4096
#define D_  1024
#define NH  16
#define NROWS (B_*KL)   // 65536

__device__ __forceinline__ void gload_lds16(const void* g, void* l) {
  __builtin_amdgcn_global_load_lds(
      (__attribute__((address_space(1))) void*)g,
      (__attribute__((address_space(3))) void*)l, 16, 0, 0);
}

// ---------- small prep kernels ----------

__global__ __launch_bounds__(256) void conv_bf16_kernel(const float* __restrict__ s,
                                                        __bf16* __restrict__ d, int n4) {
  int i = blockIdx.x * 256 + threadIdx.x;
  if (i >= n4) return;
  float4 v = reinterpret_cast<const float4*>(s)[i];
  bf16x4 o;
  o[0] = (__bf16)v.x; o[1] = (__bf16)v.y; o[2] = (__bf16)v.z; o[3] = (__bf16)v.w;
  *reinterpret_cast<bf16x4*>(d + (size_t)i * 4) = o;
}

// kvs f32 -> bf16, 67.1M elements = 16,777,216 float4.
// 16384 blocks x 256 thr x 4 float4 = exact cover.
__global__ __launch_bounds__(256) void conv_kvs_kernel(const float* __restrict__ s,
                                                       __bf16* __restrict__ d) {
  const int base = blockIdx.x * 1024 + threadIdx.x;
#pragma unroll
  for (int j = 0; j < 4; ++j) {
    int i = base + j * 256;
    float4 v = reinterpret_cast<const float4*>(s)[i];
    bf16x4 o;
    o[0] = (__bf16)v.x; o[1] = (__bf16)v.y; o[2] = (__bf16)v.z; o[3] = (__bf16)v.w;
    *reinterpret_cast<bf16x4*>(d + (size_t)i * 4) = o;
  }
}

// q[b][j] = (hs[b,:]·Wq[j,:] + bq[j]) / 8
__global__ __launch_bounds__(256) void qproj_kernel(const float* __restrict__ hs,
                                                    const float* __restrict__ Wq,
                                                    const float* __restrict__ bq,
                                                    float* __restrict__ q) {
  int gid = blockIdx.x * 256 + threadIdx.x;   // 0..16383
  int b = gid >> 10, j = gid & 1023;
  const float* x = hs + (size_t)b * D_;
  const float* w = Wq + (size_t)j * D_;
  float acc = 0.f;
  for (int i = 0; i < D_; i += 4) {
    float4 xv = *reinterpret_cast<const float4*>(x + i);
    float4 wv = *reinterpret_cast<const float4*>(w + i);
    acc += xv.x*wv.x + xv.y*wv.y + xv.z*wv.z + xv.w*wv.w;
  }
  q[gid] = (acc + bq[j]) * 0.125f;
}

// wq_eff[b,h,m] = sum_d q[b,h*64+d] * Wk[h*64+d, m];  cb[b,h] = sum_d q*bk
__global__ __launch_bounds__(256) void wqeff_kernel(const float* __restrict__ q,
                                                    const float* __restrict__ Wk,
                                                    const float* __restrict__ bk,
                                                    float* __restrict__ wqe,
                                                    float* __restrict__ cb) {
  const int h = blockIdx.x, b = blockIdx.y;
  const int tid = threadIdx.x;
  __shared__ float ql[64];
  if (tid < 64) ql[tid] = q[(size_t)b * D_ + h * 64 + tid];
  __syncthreads();
  float a0 = 0, a1 = 0, a2 = 0, a3 = 0;
  for (int d = 0; d < 64; ++d) {
    float qv = ql[d];
    const float* wr = Wk + (size_t)(h * 64 + d) * D_;
    a0 += qv * wr[tid];
    a1 += qv * wr[tid + 256];
    a2 += qv * wr[tid + 512];
    a3 += qv * wr[tid + 768];
  }
  float* o = wqe + ((size_t)b * NH + h) * D_;
  o[tid] = a0; o[tid + 256] = a1; o[tid + 512] = a2; o[tid + 768] = a3;
  if (tid < 64) {
    float p = ql[tid] * bk[h * 64 + tid];
    p += __shfl_down(p, 32); p += __shfl_down(p, 16); p += __shfl_down(p, 8);
    p += __shfl_down(p, 4);  p += __shfl_down(p, 2);  p += __shfl_down(p, 1);
    if (tid == 0) cb[b * NH + h] = p;
  }
}

// attn[row][h] = clip(kvs[row,:]·wq_eff[b,h,:] + cb[b,h], 0, 1)  -- all f32
__global__ __launch_bounds__(256) void scores_kernel(const float* __restrict__ kvs,
                                                     const float* __restrict__ wqe,
                                                     const float* __restrict__ cb,
                                                     float* __restrict__ attn) {
  __shared__ float4 wq4[NH * 256];   // 64 KiB, float4-slot XOR-swizzled by head
  const int b = blockIdx.y;
  const int chunk = blockIdx.x;      // 64 rows per block
  const int tid = threadIdx.x;
  for (int i = tid; i < NH * 256; i += 256) {
    int h = i >> 8, i4 = i & 255;
    wq4[h * 256 + (i4 ^ h)] =
        reinterpret_cast<const float4*>(wqe + ((size_t)b * NH + h) * D_)[i4];
  }
  __syncthreads();
  const int lane = tid & 63, w = tid >> 6;
  const int h = lane & 15, qt = lane >> 4;   // lane = head + 16*quarter
  const float c = cb[b * NH + h];
  for (int g = 0; g < 4; ++g) {
    const int row0 = chunk * 64 + w * 16 + g * 4;
    const float* x = kvs + ((size_t)b * KL + row0) * D_;
    float a0 = 0, a1 = 0, a2 = 0, a3 = 0;
    for (int it = 0; it < 64; ++it) {
      const int i4 = qt * 64 + it;
      float4 wv = wq4[h * 256 + (i4 ^ h)];
      const float* xm = x + i4 * 4;
      float4 r0 = *reinterpret_cast<const float4*>(xm);
      float4 r1 = *reinterpret_cast<const float4*>(xm + D_);
      float4 r2 = *reinterpret_cast<const float4*>(xm + 2 * D_);
      float4 r3 = *reinterpret_cast<const float4*>(xm + 3 * D_);
      a0 += r0.x*wv.x + r0.y*wv.y + r0.z*wv.z + r0.w*wv.w;
      a1 += r1.x*wv.x + r1.y*wv.y + r1.z*wv.z + r1.w*wv.w;
      a2 += r2.x*wv.x + r2.y*wv.y + r2.z*wv.z + r2.w*wv.w;
      a3 += r3.x*wv.x + r3.y*wv.y + r3.z*wv.z + r3.w*wv.w;
    }
    a0 += __shfl_xor(a0, 16); a0 += __shfl_xor(a0, 32);
    a1 += __shfl_xor(a1, 16); a1 += __shfl_xor(a1, 32);
    a2 += __shfl_xor(a2, 16); a2 += __shfl_xor(a2, 32);
    a3 += __shfl_xor(a3, 16); a3 += __shfl_xor(a3, 32);
    if (qt == 0) {
      size_t base = ((size_t)b * KL + row0) * NH + h;
      attn[base         ] = fminf(fmaxf(a0 + c, 0.f), 1.f);
      attn[base +    NH ] = fminf(fmaxf(a1 + c, 0.f), 1.f);
      attn[base + 2 * NH] = fminf(fmaxf(a2 + c, 0.f), 1.f);
      attn[base + 3 * NH] = fminf(fmaxf(a3 + c, 0.f), 1.f);
    }
  }
}

// ---------- 128x128 / BK=64 bf16 MFMA GEMM (NT: C = A @ Bt^T) ----------
// Both operands bf16 via global_load_lds.
// GATE:  C[row,col] = bf16((acc + bias[col]) * gate[row*16 + col/64])
// else:  C[row,col] = f32(acc + bias[col])
template <bool GATE>
__global__ __launch_bounds__(256) void gemm_nt(const __bf16* __restrict__ A,
                                               const __bf16* __restrict__ Bt,
                                               const float* __restrict__ bias,
                                               const float* __restrict__ gate,
                                               void* __restrict__ Cp) {
  constexpr int BK = 64;
  __shared__ __bf16 As[128 * BK];
  __shared__ __bf16 Bs[128 * BK];
  const int tid = threadIdx.x;
  const int lane = tid & 63, wid = tid >> 6;
  const int wm = wid >> 1, wn = wid & 1;
  // bijective XCD swizzle: 4096 blocks, 8 XCDs -> each XCD owns 64 m-tiles x all 8 n-tiles
  const int bswz = (blockIdx.x & 7) * 512 + (blockIdx.x >> 3);
  const int m0 = (bswz >> 3) * 128;
  const int n0 = (bswz & 7) * 128;
  const int r16 = lane & 15, kgrp = lane >> 4;

  f32x4 acc[4][4] = {};

  for (int kt = 0; kt < 16; ++kt) {
    const int k0 = kt * BK;
#pragma unroll
    for (int j = 0; j < 4; ++j) {
      const int chunk = j * 4 + wid;                // 0..15
      const int row = chunk * 8 + (lane >> 3);
      const int col = (lane & 7) * 8;
      gload_lds16(A + (size_t)(m0 + row) * D_ + k0 + col, &As[chunk * 512]);
    }
#pragma unroll
    for (int j = 0; j < 4; ++j) {
      const int chunk = j * 4 + wid;
      const int row = chunk * 8 + (lane >> 3);
      const int col = (lane & 7) * 8;
      gload_lds16(Bt + (size_t)(n0 + row) * D_ + k0 + col, &Bs[chunk * 512]);
    }
    __syncthreads();
#pragma unroll
    for (int kk = 0; kk < 2; ++kk) {
      bf16x8 av[4], bv4[4];
#pragma unroll
      for (int f = 0; f < 4; ++f) {
        av[f]  = *reinterpret_cast<const bf16x8*>(&As[(wm * 64 + f * 16 + r16) * BK + kk * 32 + kgrp * 8]);
        bv4[f] = *reinterpret_cast<const bf16x8*>(&Bs[(wn * 64 + f * 16 + r16) * BK + kk * 32 + kgrp * 8]);
      }
#pragma unroll
      for (int fm = 0; fm < 4; ++fm)
#pragma unroll
        for (int fn = 0; fn < 4; ++fn)
          acc[fm][fn] = __builtin_amdgcn_mfma_f32_16x16x32_bf16(av[fm], bv4[fn], acc[fm][fn], 0, 0, 0);
    }
    if (kt != 15) __syncthreads();
  }

  // epilogue. C/D layout: col = lane&15, row = (lane>>4)*4 + reg
  const int head = (n0 >> 6) + wn;   // uniform over fn (fn*16+r16 < 64)
#pragma unroll
  for (int fm = 0; fm < 4; ++fm) {
    const int rowb = m0 + wm * 64 + fm * 16 + kgrp * 4;
#pragma unroll
    for (int fn = 0; fn < 4; ++fn) {
      const int col = n0 + wn * 64 + fn * 16 + r16;
      const float bc = bias[col];
#pragma unroll
      for (int r = 0; r < 4; ++r) {
        const int row = rowb + r;
        if constexpr (GATE) {
          float g = gate[(size_t)row * NH + head];
          ((__bf16*)Cp)[(size_t)row * D_ + col] = (__bf16)((acc[fm][fn][r] + bc) * g);
        } else {
          ((float*)Cp)[(size_t)row * D_ + col] = acc[fm][fn][r] + bc;
        }
      }
    }
  }
}

extern "C" void kernel_launch(void* const* d_in, const int* in_sizes, int n_in,
                              void* d_out, int out_size, void* d_ws, size_t ws_size,
                              hipStream_t stream) {
  const float* hs  = (const float*)d_in[0];   // [16,1,1024]
  const float* kvs = (const float*)d_in[1];   // [16,4096,1024]
  const float* Wq  = (const float*)d_in[2];
  const float* bq  = (const float*)d_in[3];
  const float* Wk  = (const float*)d_in[4];
  const float* bk  = (const float*)d_in[5];
  const float* Wv  = (const float*)d_in[6];
  const float* bv  = (const float*)d_in[7];
  const float* Wo  = (const float*)d_in[8];
  const float* bo  = (const float*)d_in[9];
  float* out = (float*)d_out;

  char* w = (char*)d_ws;
  __bf16* ctx  = (__bf16*)w;  w += (size_t)NROWS * D_ * 2;   // 128 MB gated context (bf16)
  float*  attn = (float*)w;   w += (size_t)NROWS * NH * 4;   // 4 MB gate [row][head]
  __bf16* WvB  = (__bf16*)w;  w += (size_t)D_ * D_ * 2;      // 2 MB
  __bf16* WoB  = (__bf16*)w;  w += (size_t)D_ * D_ * 2;      // 2 MB
  float*  wqe  = (float*)w;   w += (size_t)B_ * NH * D_ * 4; // 1 MB
  float*  qbuf = (float*)w;   w += (size_t)B_ * D_ * 4;      // 64 KB
  float*  cbuf = (float*)w;   w += B_ * NH * 4;              // 1 KB

  // bf16 copy of kvs lives in d_out (128 MB of its 256 MB); consumed by GEMM1,
  // then fully overwritten by GEMM2's epilogue. No cross-call state.
  __bf16* kvsB = (__bf16*)d_out;

  conv_bf16_kernel<<<1024, 256, 0, stream>>>(Wv, WvB, 262144);
  conv_bf16_kernel<<<1024, 256, 0, stream>>>(Wo, WoB, 262144);
  conv_kvs_kernel<<<16384, 256, 0, stream>>>(kvs, kvsB);
  qproj_kernel<<<64, 256, 0, stream>>>(hs, Wq, bq, qbuf);
  wqeff_kernel<<<dim3(NH, B_), 256, 0, stream>>>(qbuf, Wk, bk, wqe, cbuf);
  scores_kernel<<<dim3(64, B_), 256, 0, stream>>>(kvs, wqe, cbuf, attn);
  gemm_nt<true ><<<4096, 256, 0, stream>>>(kvsB, WvB, bv, attn, ctx);
  gemm_nt<false><<<4096, 256, 0, stream>>>(ctx, WoB, bo, (const float*)nullptr, (void*)out);
}

// Round 7
// 680.699 us; speedup vs baseline: 1.1394x; 1.1394x over previous
//
#include <hip/hip_runtime.h>
#include <hip/hip_bf16.h>
#include <stdint.h>

typedef __bf16 bf16x8 __attribute__((ext_vector_type(8)));
typedef __bf16 bf16x4 __attribute__((ext_vector_type(4)));
typedef float  f32x4  __attribute__((ext_vector_type(4)));

#define B_  16
#define KL  4096
#define D_  1024
#define NH  16
#define NROWS (B_*KL)   // 65536

__device__ __forceinline__ void gload_lds16(const void* g, void* l) {
  __builtin_amdgcn_global_load_lds(
      (__attribute__((address_space(1))) void*)g,
      (__attribute__((address_space(3))) void*)l, 16, 0, 0);
}

// ---------- small prep kernels ----------

__global__ __launch_bounds__(256) void conv_bf16_kernel(const float* __restrict__ s,
                                                        __bf16* __restrict__ d, int n4) {
  int i = blockIdx.x * 256 + threadIdx.x;
  if (i >= n4) return;
  float4 v = reinterpret_cast<const float4*>(s)[i];
  bf16x4 o;
  o[0] = (__bf16)v.x; o[1] = (__bf16)v.y; o[2] = (__bf16)v.z; o[3] = (__bf16)v.w;
  *reinterpret_cast<bf16x4*>(d + (size_t)i * 4) = o;
}

// kvs f32 -> bf16, 16,777,216 float4. 16384 blocks x 256 thr x 4.
__global__ __launch_bounds__(256) void conv_kvs_kernel(const float* __restrict__ s,
                                                       __bf16* __restrict__ d) {
  const int base = blockIdx.x * 1024 + threadIdx.x;
#pragma unroll
  for (int j = 0; j < 4; ++j) {
    int i = base + j * 256;
    float4 v = reinterpret_cast<const float4*>(s)[i];
    bf16x4 o;
    o[0] = (__bf16)v.x; o[1] = (__bf16)v.y; o[2] = (__bf16)v.z; o[3] = (__bf16)v.w;
    *reinterpret_cast<bf16x4*>(d + (size_t)i * 4) = o;
  }
}

// q[b][j] = (hs[b,:]·Wq[j,:] + bq[j]) / 8
__global__ __launch_bounds__(256) void qproj_kernel(const float* __restrict__ hs,
                                                    const float* __restrict__ Wq,
                                                    const float* __restrict__ bq,
                                                    float* __restrict__ q) {
  int gid = blockIdx.x * 256 + threadIdx.x;   // 0..16383
  int b = gid >> 10, j = gid & 1023;
  const float* x = hs + (size_t)b * D_;
  const float* w = Wq + (size_t)j * D_;
  float acc = 0.f;
  for (int i = 0; i < D_; i += 4) {
    float4 xv = *reinterpret_cast<const float4*>(x + i);
    float4 wv = *reinterpret_cast<const float4*>(w + i);
    acc += xv.x*wv.x + xv.y*wv.y + xv.z*wv.z + xv.w*wv.w;
  }
  q[gid] = (acc + bq[j]) * 0.125f;
}

// wq_eff[b,h,m] = sum_d q[b,h*64+d] * Wk[h*64+d, m];  cb[b,h] = sum_d q*bk
__global__ __launch_bounds__(256) void wqeff_kernel(const float* __restrict__ q,
                                                    const float* __restrict__ Wk,
                                                    const float* __restrict__ bk,
                                                    float* __restrict__ wqe,
                                                    float* __restrict__ cb) {
  const int h = blockIdx.x, b = blockIdx.y;
  const int tid = threadIdx.x;
  __shared__ float ql[64];
  if (tid < 64) ql[tid] = q[(size_t)b * D_ + h * 64 + tid];
  __syncthreads();
  float a0 = 0, a1 = 0, a2 = 0, a3 = 0;
  for (int d = 0; d < 64; ++d) {
    float qv = ql[d];
    const float* wr = Wk + (size_t)(h * 64 + d) * D_;
    a0 += qv * wr[tid];
    a1 += qv * wr[tid + 256];
    a2 += qv * wr[tid + 512];
    a3 += qv * wr[tid + 768];
  }
  float* o = wqe + ((size_t)b * NH + h) * D_;
  o[tid] = a0; o[tid + 256] = a1; o[tid + 512] = a2; o[tid + 768] = a3;
  if (tid < 64) {
    float p = ql[tid] * bk[h * 64 + tid];
    p += __shfl_down(p, 32); p += __shfl_down(p, 16); p += __shfl_down(p, 8);
    p += __shfl_down(p, 4);  p += __shfl_down(p, 2);  p += __shfl_down(p, 1);
    if (tid == 0) cb[b * NH + h] = p;
  }
}

// attn[row][h] = clip(kvs[row,:]·wq_eff[b,h,:] + cb[b,h], 0, 1)  -- all f32
__global__ __launch_bounds__(256) void scores_kernel(const float* __restrict__ kvs,
                                                     const float* __restrict__ wqe,
                                                     const float* __restrict__ cb,
                                                     float* __restrict__ attn) {
  __shared__ float4 wq4[NH * 256];   // 64 KiB, float4-slot XOR-swizzled by head
  const int b = blockIdx.y;
  const int chunk = blockIdx.x;      // 64 rows per block
  const int tid = threadIdx.x;
  for (int i = tid; i < NH * 256; i += 256) {
    int h = i >> 8, i4 = i & 255;
    wq4[h * 256 + (i4 ^ h)] =
        reinterpret_cast<const float4*>(wqe + ((size_t)b * NH + h) * D_)[i4];
  }
  __syncthreads();
  const int lane = tid & 63, w = tid >> 6;
  const int h = lane & 15, qt = lane >> 4;   // lane = head + 16*quarter
  const float c = cb[b * NH + h];
  for (int g = 0; g < 4; ++g) {
    const int row0 = chunk * 64 + w * 16 + g * 4;
    const float* x = kvs + ((size_t)b * KL + row0) * D_;
    float a0 = 0, a1 = 0, a2 = 0, a3 = 0;
    for (int it = 0; it < 64; ++it) {
      const int i4 = qt * 64 + it;
      float4 wv = wq4[h * 256 + (i4 ^ h)];
      const float* xm = x + i4 * 4;
      float4 r0 = *reinterpret_cast<const float4*>(xm);
      float4 r1 = *reinterpret_cast<const float4*>(xm + D_);
      float4 r2 = *reinterpret_cast<const float4*>(xm + 2 * D_);
      float4 r3 = *reinterpret_cast<const float4*>(xm + 3 * D_);
      a0 += r0.x*wv.x + r0.y*wv.y + r0.z*wv.z + r0.w*wv.w;
      a1 += r1.x*wv.x + r1.y*wv.y + r1.z*wv.z + r1.w*wv.w;
      a2 += r2.x*wv.x + r2.y*wv.y + r2.z*wv.z + r2.w*wv.w;
      a3 += r3.x*wv.x + r3.y*wv.y + r3.z*wv.z + r3.w*wv.w;
    }
    a0 += __shfl_xor(a0, 16); a0 += __shfl_xor(a0, 32);
    a1 += __shfl_xor(a1, 16); a1 += __shfl_xor(a1, 32);
    a2 += __shfl_xor(a2, 16); a2 += __shfl_xor(a2, 32);
    a3 += __shfl_xor(a3, 16); a3 += __shfl_xor(a3, 32);
    if (qt == 0) {
      size_t base = ((size_t)b * KL + row0) * NH + h;
      attn[base         ] = fminf(fmaxf(a0 + c, 0.f), 1.f);
      attn[base +    NH ] = fminf(fmaxf(a1 + c, 0.f), 1.f);
      attn[base + 2 * NH] = fminf(fmaxf(a2 + c, 0.f), 1.f);
      attn[base + 3 * NH] = fminf(fmaxf(a3 + c, 0.f), 1.f);
    }
  }
}

// ---------- 256x256 / BK=64 bf16 MFMA GEMM, 2-phase dbuf + counted vmcnt ----------
// C = A @ Bt^T, M=65536, N=K=1024. 512 threads = 8 waves (2M x 4N).
// Phase p computes A-half-p x FULL B. Staging order per tile: B full (4/wave),
// A half0 (2/wave), A half1 (2/wave). Counted-vmcnt invariant (per wave):
//   end of phase 2 (and prologue): 8 outstanding -> vmcnt(2) retires B_next +
//   A_next_h0 (exactly what phase 1 computes on); A_next_h1 stays in flight.
//   end of phase 1: 8 outstanding -> vmcnt(6) retires exactly A_cur_h1
//   (what phase 2 computes on). Loads always span barriers; never vmcnt(0)
//   mid-loop. LDS: 2 x (A 32KB + B 32KB) = 128 KiB.
// T2 swizzle (both-sides involution): LDS[R][j] holds global slot j^(R&7);
// read slot k as j = k^(R&7); all fragment rows have R&7 == r16&7.
template <bool GATE>
__global__ __launch_bounds__(512, 2) void gemm_nt(const __bf16* __restrict__ A,
                                                  const __bf16* __restrict__ Bt,
                                                  const float* __restrict__ bias,
                                                  const float* __restrict__ gate,
                                                  void* __restrict__ Cp) {
  __shared__ __bf16 As[2][256 * 64];
  __shared__ __bf16 Bs[2][256 * 64];
  const int tid = threadIdx.x;
  const int lane = tid & 63, wid = tid >> 6;
  const int wm = wid >> 2, wn = wid & 3;           // 2 x 4 waves
  const int r16 = lane & 15, kgrp = lane >> 4;
  // bijective XCD swizzle: 1024 blocks, 8 XCDs, 128 blocks each
  const int bswz = (blockIdx.x & 7) * 128 + (blockIdx.x >> 3);
  const int m0 = (bswz >> 2) * 256;
  const int n0 = (bswz & 3) * 256;

  // staging: chunk c = 8 rows x 64 cols (1 KB), LDS linear row-major.
  const int srow = lane >> 3;                    // row within chunk
  const int scol = ((lane & 7) ^ srow) * 8;      // pre-swizzled source col (elems)

  // swizzled ds_read slots (elems): slot(kk) = ((kk*4+kgrp) ^ (r16&7)) * 8
  const int sw0 = ((kgrp) ^ (r16 & 7)) * 8;
  const int sw1 = ((4 + kgrp) ^ (r16 & 7)) * 8;

  f32x4 acc[8][4] = {};   // [mh*4+f][nh*2+g]

#define STAGE_B_FULL(dstbuf, k0)                                                \
  {                                                                             \
    _Pragma("unroll") for (int j = 0; j < 4; ++j) {                             \
      const int c = wid * 4 + j;                                                \
      gload_lds16(Bt + (size_t)(n0 + c * 8 + srow) * D_ + (k0) + scol,          \
                  &(dstbuf)[c * 512]);                                          \
    }                                                                           \
  }
#define STAGE_A_HALF(dstbuf, k0, h)                                             \
  {                                                                             \
    _Pragma("unroll") for (int j = 0; j < 2; ++j) {                             \
      const int c = (h) * 16 + wid * 2 + j;                                     \
      gload_lds16(A + (size_t)(m0 + c * 8 + srow) * D_ + (k0) + scol,           \
                  &(dstbuf)[c * 512]);                                          \
    }                                                                           \
  }

#define COMPUTE_HALF(Ab, Bb, mh)                                                 \
  {                                                                              \
    _Pragma("unroll") for (int kk = 0; kk < 2; ++kk) {                           \
      const int sw = kk ? sw1 : sw0;                                             \
      bf16x8 av[4];                                                              \
      _Pragma("unroll") for (int f = 0; f < 4; ++f)                              \
        av[f] = *reinterpret_cast<const bf16x8*>(                                \
            &(Ab)[((mh) * 128 + wm * 64 + f * 16 + r16) * 64 + sw]);             \
      _Pragma("unroll") for (int nh = 0; nh < 2; ++nh) {                         \
        bf16x8 bv[2];                                                            \
        _Pragma("unroll") for (int g = 0; g < 2; ++g)                            \
          bv[g] = *reinterpret_cast<const bf16x8*>(                              \
              &(Bb)[(nh * 128 + wn * 32 + g * 16 + r16) * 64 + sw]);             \
        __builtin_amdgcn_s_setprio(1);                                           \
        _Pragma("unroll") for (int f = 0; f < 4; ++f)                            \
          _Pragma("unroll") for (int g = 0; g < 2; ++g)                          \
            acc[(mh) * 4 + f][nh * 2 + g] = __builtin_amdgcn_mfma_f32_16x16x32_bf16( \
                av[f], bv[g], acc[(mh) * 4 + f][nh * 2 + g], 0, 0, 0);           \
        __builtin_amdgcn_s_setprio(0);                                           \
      }                                                                          \
    }                                                                            \
  }

  // prologue: B0 full, A0 h0, A0 h1. Retire B0+A0h0 (oldest 6), keep A0h1 in flight.
  STAGE_B_FULL(Bs[0], 0);
  STAGE_A_HALF(As[0], 0, 0);
  STAGE_A_HALF(As[0], 0, 1);
  asm volatile("s_waitcnt vmcnt(2)" ::: "memory");
  __builtin_amdgcn_s_barrier();

  const int NT = D_ / 64;   // 16
  for (int t = 0; t < NT; ++t) {
    __bf16* Ab = (t & 1) ? As[1] : As[0];
    __bf16* Bb = (t & 1) ? Bs[1] : Bs[0];
    __bf16* An = (t & 1) ? As[0] : As[1];
    __bf16* Bn = (t & 1) ? Bs[0] : Bs[1];
    const int k1 = (t + 1) * 64;
    // ---- phase 1: stage B_next full + A_next h0, compute A-half-0 x B ----
    if (t < NT - 1) {
      STAGE_B_FULL(Bn, k1);
      STAGE_A_HALF(An, k1, 0);
    }
    COMPUTE_HALF(Ab, Bb, 0);
    asm volatile("s_waitcnt lgkmcnt(0)" ::: "memory");
    if (t < NT - 1) asm volatile("s_waitcnt vmcnt(6)" ::: "memory");  // retire A_t h1
    else            asm volatile("s_waitcnt vmcnt(0)" ::: "memory");
    __builtin_amdgcn_s_barrier();
    // ---- phase 2: stage A_next h1, compute A-half-1 x B ----
    if (t < NT - 1) STAGE_A_HALF(An, k1, 1);
    COMPUTE_HALF(Ab, Bb, 1);
    if (t < NT - 1) {
      asm volatile("s_waitcnt lgkmcnt(0)" ::: "memory");
      asm volatile("s_waitcnt vmcnt(2)" ::: "memory");  // retire B_next + A_next h0
      __builtin_amdgcn_s_barrier();
    }
  }

  // epilogue. C/D layout: col = lane&15, row = (lane>>4)*4 + reg
#pragma unroll
  for (int mh = 0; mh < 2; ++mh) {
#pragma unroll
    for (int f = 0; f < 4; ++f) {
      const int row0 = m0 + mh * 128 + wm * 64 + f * 16 + kgrp * 4;
#pragma unroll
      for (int nh = 0; nh < 2; ++nh) {
#pragma unroll
        for (int g = 0; g < 2; ++g) {
          const int col = n0 + nh * 128 + wn * 32 + g * 16 + r16;
          const float bc = bias[col];
          const int head = col >> 6;
          f32x4 v = acc[mh * 4 + f][nh * 2 + g];
#pragma unroll
          for (int r = 0; r < 4; ++r) {
            const int row = row0 + r;
            if constexpr (GATE) {
              float gg = gate[(size_t)row * NH + head];
              ((__bf16*)Cp)[(size_t)row * D_ + col] = (__bf16)((v[r] + bc) * gg);
            } else {
              ((float*)Cp)[(size_t)row * D_ + col] = v[r] + bc;
            }
          }
        }
      }
    }
  }
#undef STAGE_B_FULL
#undef STAGE_A_HALF
#undef COMPUTE_HALF
}

extern "C" void kernel_launch(void* const* d_in, const int* in_sizes, int n_in,
                              void* d_out, int out_size, void* d_ws, size_t ws_size,
                              hipStream_t stream) {
  const float* hs  = (const float*)d_in[0];   // [16,1,1024]
  const float* kvs = (const float*)d_in[1];   // [16,4096,1024]
  const float* Wq  = (const float*)d_in[2];
  const float* bq  = (const float*)d_in[3];
  const float* Wk  = (const float*)d_in[4];
  const float* bk  = (const float*)d_in[5];
  const float* Wv  = (const float*)d_in[6];
  const float* bv  = (const float*)d_in[7];
  const float* Wo  = (const float*)d_in[8];
  const float* bo  = (const float*)d_in[9];
  float* out = (float*)d_out;

  char* w = (char*)d_ws;
  __bf16* ctx  = (__bf16*)w;  w += (size_t)NROWS * D_ * 2;   // 128 MB gated context (bf16)
  float*  attn = (float*)w;   w += (size_t)NROWS * NH * 4;   // 4 MB gate [row][head]
  __bf16* WvB  = (__bf16*)w;  w += (size_t)D_ * D_ * 2;      // 2 MB
  __bf16* WoB  = (__bf16*)w;  w += (size_t)D_ * D_ * 2;      // 2 MB
  float*  wqe  = (float*)w;   w += (size_t)B_ * NH * D_ * 4; // 1 MB
  float*  qbuf = (float*)w;   w += (size_t)B_ * D_ * 4;      // 64 KB
  float*  cbuf = (float*)w;   w += B_ * NH * 4;              // 1 KB

  // bf16 copy of kvs lives in d_out (128 MB of its 256 MB); consumed by GEMM1,
  // then fully overwritten by GEMM2's epilogue. No cross-call state.
  __bf16* kvsB = (__bf16*)d_out;

  conv_bf16_kernel<<<1024, 256, 0, stream>>>(Wv, WvB, 262144);
  conv_bf16_kernel<<<1024, 256, 0, stream>>>(Wo, WoB, 262144);
  conv_kvs_kernel<<<16384, 256, 0, stream>>>(kvs, kvsB);
  qproj_kernel<<<64, 256, 0, stream>>>(hs, Wq, bq, qbuf);
  wqeff_kernel<<<dim3(NH, B_), 256, 0, stream>>>(qbuf, Wk, bk, wqe, cbuf);
  scores_kernel<<<dim3(64, B_), 256, 0, stream>>>(kvs, wqe, cbuf, attn);
  gemm_nt<true ><<<1024, 512, 0, stream>>>(kvsB, WvB, bv, attn, ctx);
  gemm_nt<false><<<1024, 512, 0, stream>>>(ctx, WoB, bo, (const float*)nullptr, (void*)out);
}